// Round 1
// baseline (2998.119 us; speedup 1.0000x reference)
//
#include <hip/hip_runtime.h>

typedef unsigned short u16;
typedef unsigned int u32;
typedef float f32x4 __attribute__((ext_vector_type(4)));
typedef short s16x8 __attribute__((ext_vector_type(8)));
typedef u16 u16x4 __attribute__((ext_vector_type(4)));
typedef u16 u16x8 __attribute__((ext_vector_type(8)));

// ---------- helpers ----------
__device__ __forceinline__ u16 f2bf(float x) {           // RNE f32->bf16
    u32 u = __builtin_bit_cast(u32, x);
    u += 0x7fffu + ((u >> 16) & 1u);
    return (u16)(u >> 16);
}
__device__ __forceinline__ float sigm(float x) { return 1.f / (1.f + __expf(-x)); }
__device__ __forceinline__ float tanh_fast(float x) {
    float e = __expf(-2.f * fabsf(x));
    float t = (1.f - e) / (1.f + e);
    return copysignf(t, x);
}
__device__ __forceinline__ void gload16(const void* g, void* l) {
    __builtin_amdgcn_global_load_lds((const __attribute__((address_space(1))) void*)g,
                                     (__attribute__((address_space(3))) void*)l, 16, 0, 0);
}
__device__ __forceinline__ void mfma_bf16(s16x8 a, s16x8 b, f32x4& acc) {
    asm volatile("v_mfma_f32_16x16x32_bf16 %0, %1, %2, %0" : "+v"(acc) : "v"(a), "v"(b));
}

// ---------- f32 -> bf16 convert, 8 elems/thread, exact grid ----------
__global__ __launch_bounds__(256) void k_cvt(const float* __restrict__ in, u16* __restrict__ out) {
    size_t i = (size_t)blockIdx.x * 256 + threadIdx.x;
    const f32x4* p = (const f32x4*)in + i * 2;
    f32x4 a = p[0], b = p[1];
    u16x8 v;
    v[0] = f2bf(a[0]); v[1] = f2bf(a[1]); v[2] = f2bf(a[2]); v[3] = f2bf(a[3]);
    v[4] = f2bf(b[0]); v[5] = f2bf(b[1]); v[6] = f2bf(b[2]); v[7] = f2bf(b[3]);
    ((u16x8*)out)[i] = v;
}

// ---------- A[b][d][s] = ew[b*1024 + s*32 + d] / 32 ----------
__global__ __launch_bounds__(256) void k_buildA(const float* __restrict__ ew, float* __restrict__ A) {
    int i = blockIdx.x * 256 + threadIdx.x;           // 131072 total
    int b = i >> 10, rem = i & 1023, s = rem >> 5, d = rem & 31;
    A[(b << 10) + (d << 5) + s] = ew[i] * 0.03125f;
}

// ---------- bf16 GEMM  C[M,N] = A[M,K] * B[N,K]^T  (m97 structure) ----------
// 128x128 tile, BK=32, 256 thr (4 waves 2x2), ragged N supported (M%128==0, K%32==0)
__global__ __launch_bounds__(256) void k_gemm(const u16* __restrict__ A, const u16* __restrict__ B,
                                              float* __restrict__ C, int M, int N, int K) {
    __shared__ u16 lA[4096], lB[4096];
    const int tid = threadIdx.x, wave = tid >> 6, lane = tid & 63;
    const int n0 = blockIdx.x * 128, m0 = blockIdx.y * 128;
    const int srow = tid >> 2, scol = (tid & 3) * 8;
    const size_t Ks = (size_t)K;
    const u16* gA0 = A + (size_t)(m0 + srow) * Ks + scol;
    const u16* gA1 = gA0 + 64 * Ks;
    int br0 = n0 + srow;      if (br0 > N - 1) br0 = N - 1;
    int br1 = n0 + 64 + srow; if (br1 > N - 1) br1 = N - 1;
    const u16* gB0 = B + (size_t)br0 * Ks + scol;
    const u16* gB1 = B + (size_t)br1 * Ks + scol;
    u16* lAw0 = lA + wave * 512; u16* lAw1 = lA + 2048 + wave * 512;
    u16* lBw0 = lB + wave * 512; u16* lBw1 = lB + 2048 + wave * 512;
    const int wm = wave >> 1, wn = wave & 1;
    const int fr = lane & 15, fk = (lane >> 4) * 8;

    f32x4 acc[4][4] = {};
    for (int kt = 0; kt < K; kt += 32) {
        gload16(gA0 + kt, lAw0);
        gload16(gA1 + kt, lAw1);
        gload16(gB0 + kt, lBw0);
        gload16(gB1 + kt, lBw1);
        __syncthreads();                               // drains vmcnt
        s16x8 av[4], bv[4];
#pragma unroll
        for (int i = 0; i < 4; ++i) av[i] = *(const s16x8*)(lA + (wm * 64 + i * 16 + fr) * 32 + fk);
#pragma unroll
        for (int j = 0; j < 4; ++j) bv[j] = *(const s16x8*)(lB + (wn * 64 + j * 16 + fr) * 32 + fk);
#pragma unroll
        for (int i = 0; i < 4; ++i)
#pragma unroll
            for (int j = 0; j < 4; ++j)
                mfma_bf16(av[i], bv[j], acc[i][j]);
        __syncthreads();
    }
    const int rowb = m0 + wm * 64 + ((lane >> 4) << 2);
    const int colb = n0 + wn * 64 + (lane & 15);
#pragma unroll
    for (int i = 0; i < 4; ++i)
#pragma unroll
        for (int j = 0; j < 4; ++j) {
            int col = colb + j * 16;
            if (col < N) {
#pragma unroll
                for (int r = 0; r < 4; ++r)
                    C[(size_t)(rowb + i * 16 + r) * N + col] = acc[i][j][r];
            }
        }
}

// ---------- per-batch 32x32 aggregation + root + bias + relu ----------
template <int H, bool OUT_BF16>
__global__ __launch_bounds__(256) void k_agg(const float* __restrict__ Grel, const float* __restrict__ Groot,
                                             const float* __restrict__ A, const float* __restrict__ bias,
                                             void* __restrict__ outp) {
    __shared__ float lA[1024];
    const int b = blockIdx.x;
    for (int i = threadIdx.x; i < 1024; i += 256) lA[i] = A[(b << 10) + i];
    __syncthreads();
    const int d0 = (threadIdx.x >> 5) * 4;
    const int jg = threadIdx.x & 31;
    const float* Gb = Grel + (size_t)b * 32 * H;
    const float* Gr = Groot + (size_t)b * 32 * H;
    for (int j0 = jg * 4; j0 < H; j0 += 128) {
        f32x4 acc[4] = {};
        for (int s = 0; s < 32; ++s) {
            f32x4 g4 = *(const f32x4*)(Gb + (size_t)s * H + j0);
#pragma unroll
            for (int dd = 0; dd < 4; ++dd) acc[dd] += lA[(d0 + dd) * 32 + s] * g4;
        }
        f32x4 bb = *(const f32x4*)(bias + j0);
#pragma unroll
        for (int dd = 0; dd < 4; ++dd) {
            int d = d0 + dd;
            f32x4 r = acc[dd] + *(const f32x4*)(Gr + (size_t)d * H + j0) + bb;
            r[0] = fmaxf(r[0], 0.f); r[1] = fmaxf(r[1], 0.f);
            r[2] = fmaxf(r[2], 0.f); r[3] = fmaxf(r[3], 0.f);
            size_t o = (size_t)(b * 32 + d) * H + j0;
            if (OUT_BF16) {
                u16x4 v; v[0] = f2bf(r[0]); v[1] = f2bf(r[1]); v[2] = f2bf(r[2]); v[3] = f2bf(r[3]);
                *(u16x4*)((u16*)outp + o) = v;
            } else {
                *(f32x4*)((float*)outp + o) = r;
            }
        }
    }
}

// ---------- LSTM layer-0 input projection: xg[t][n][g] from h2 column t ----------
__global__ __launch_bounds__(256) void k_xg0(const float* __restrict__ h2,
    const float* __restrict__ wihf, const float* __restrict__ bihf, const float* __restrict__ bhhf,
    const float* __restrict__ wihr, const float* __restrict__ bihr, const float* __restrict__ bhhr,
    float* __restrict__ xgf, float* __restrict__ xgr) {
    __shared__ float col[4096];
    const int t = blockIdx.x;
    for (int r = threadIdx.x; r < 4096; r += 256) col[r] = h2[(size_t)r * 512 + t];
    __syncthreads();
    const int dir = threadIdx.x >> 7, g = threadIdx.x & 127;
    const float* wih = dir ? wihr : wihf;
    const float bias = dir ? (bihr[g] + bhhr[g]) : (bihf[g] + bhhf[g]);
    f32x4 w[8];
#pragma unroll
    for (int q = 0; q < 8; ++q) w[q] = *(const f32x4*)(wih + g * 32 + q * 4);
    float* out = dir ? xgr : xgf;
    const f32x4* c4 = (const f32x4*)col;
    for (int n = 0; n < 128; ++n) {
        float acc = bias;
#pragma unroll
        for (int q = 0; q < 8; ++q) {
            f32x4 v = c4[n * 8 + q];
            acc += w[q][0] * v[0] + w[q][1] * v[1] + w[q][2] * v[2] + w[q][3] * v[3];
        }
        out[((size_t)t * 128 + n) * 128 + g] = acc;
    }
}

// ---------- LSTM layer-1 input projection: input = concat(hs0f, hs0r) ----------
__global__ __launch_bounds__(256) void k_xg1(const float* __restrict__ hf, const float* __restrict__ hr,
    const float* __restrict__ wihf, const float* __restrict__ bihf, const float* __restrict__ bhhf,
    const float* __restrict__ wihr, const float* __restrict__ bihr, const float* __restrict__ bhhr,
    float* __restrict__ xgf, float* __restrict__ xgr) {
    __shared__ float sin_[8192];
    const int t = blockIdx.x;
    for (int idx = threadIdx.x; idx < 8192; idx += 256) {
        int n = idx >> 6, c = idx & 63;
        sin_[idx] = (c < 32) ? hf[((size_t)t * 128 + n) * 32 + c]
                             : hr[((size_t)t * 128 + n) * 32 + (c & 31)];
    }
    __syncthreads();
    const int dir = threadIdx.x >> 7, g = threadIdx.x & 127;
    const float* wih = dir ? wihr : wihf;
    const float bias = dir ? (bihr[g] + bhhr[g]) : (bihf[g] + bhhf[g]);
    f32x4 w[16];
#pragma unroll
    for (int q = 0; q < 16; ++q) w[q] = *(const f32x4*)(wih + g * 64 + q * 4);
    float* out = dir ? xgr : xgf;
    const f32x4* s4 = (const f32x4*)sin_;
    for (int n = 0; n < 128; ++n) {
        float acc = bias;
#pragma unroll
        for (int q = 0; q < 16; ++q) {
            f32x4 v = s4[n * 16 + q];
            acc += w[q][0] * v[0] + w[q][1] * v[1] + w[q][2] * v[2] + w[q][3] * v[3];
        }
        out[((size_t)t * 128 + n) * 128 + g] = acc;
    }
}

// ---------- LSTM recurrence: grid = 2 dirs x 16 batch-chunks, 256 thr = 8 batch x 32 hidden ----------
__global__ __launch_bounds__(256) void k_lstm(const float* __restrict__ xgf, const float* __restrict__ xgr,
                                              const float* __restrict__ whhf, const float* __restrict__ whhr,
                                              float* __restrict__ hsf, float* __restrict__ hsr) {
    const int dir = blockIdx.x >> 4;
    const int n0 = (blockIdx.x & 15) * 8;
    const int bl = threadIdx.x >> 5, j = threadIdx.x & 31;
    const float* xg = dir ? xgr : xgf;
    const float* whh = dir ? whhr : whhf;
    float* hs = dir ? hsr : hsf;
    __shared__ float hb[256];
    f32x4 w[4][8];
#pragma unroll
    for (int q = 0; q < 4; ++q)
#pragma unroll
        for (int k = 0; k < 8; ++k)
            w[q][k] = *(const f32x4*)(whh + (size_t)(q * 32 + j) * 32 + k * 4);
    hb[threadIdx.x] = 0.f;
    float c = 0.f;
    __syncthreads();
    const f32x4* hb4 = (const f32x4*)hb;
    for (int ts = 0; ts < 512; ++ts) {
        const int tt = dir ? (511 - ts) : ts;
        const float* xp = xg + ((size_t)tt * 128 + n0 + bl) * 128;
        float gi = xp[j], gf = xp[32 + j], gg = xp[64 + j], go = xp[96 + j];
#pragma unroll
        for (int k = 0; k < 8; ++k) {
            f32x4 hv = hb4[bl * 8 + k];
            gi += w[0][k][0] * hv[0] + w[0][k][1] * hv[1] + w[0][k][2] * hv[2] + w[0][k][3] * hv[3];
            gf += w[1][k][0] * hv[0] + w[1][k][1] * hv[1] + w[1][k][2] * hv[2] + w[1][k][3] * hv[3];
            gg += w[2][k][0] * hv[0] + w[2][k][1] * hv[1] + w[2][k][2] * hv[2] + w[2][k][3] * hv[3];
            go += w[3][k][0] * hv[0] + w[3][k][1] * hv[1] + w[3][k][2] * hv[2] + w[3][k][3] * hv[3];
        }
        c = sigm(gf) * c + sigm(gi) * tanh_fast(gg);
        float h = sigm(go) * tanh_fast(c);
        hs[((size_t)tt * 128 + n0 + bl) * 32 + j] = h;
        __syncthreads();
        hb[threadIdx.x] = h;
        __syncthreads();
    }
}

// ---------- m1 init to bias ----------
__global__ __launch_bounds__(256) void k_m1init(float* __restrict__ m1, const float* __restrict__ bm1) {
    int i = blockIdx.x * 256 + threadIdx.x;
    m1[i] = bm1[i & 127];
}

// ---------- split-K MLP: block = 4 time-steps, atomicAdd partials into m1[n][p] ----------
__global__ __launch_bounds__(256) void k_mlp(const float* __restrict__ hf, const float* __restrict__ hr,
                                             const float* __restrict__ wm1, float* __restrict__ m1) {
    __shared__ float sa[8192], sb[8192];
    const int t0 = blockIdx.x * 4;
    const int tn = threadIdx.x >> 4, tp = threadIdx.x & 15;
    float acc[8][8] = {};
    for (int t = t0; t < t0 + 4; ++t) {
        __syncthreads();
        for (int idx = threadIdx.x; idx < 8192; idx += 256) {
            int n = idx >> 6, k = idx & 63;
            sa[idx] = (k < 32) ? hf[((size_t)t * 128 + n) * 32 + k]
                               : hr[((size_t)t * 128 + n) * 32 + (k & 31)];
            sb[idx] = wm1[(size_t)n * 32768 + t * 64 + k];
        }
        __syncthreads();
        const f32x4* sa4 = (const f32x4*)sa;
        const f32x4* sb4 = (const f32x4*)sb;
        for (int k4 = 0; k4 < 16; ++k4) {
            f32x4 a[8], b[8];
#pragma unroll
            for (int u = 0; u < 8; ++u) a[u] = sa4[(tn * 8 + u) * 16 + k4];
#pragma unroll
            for (int u = 0; u < 8; ++u) b[u] = sb4[(tp * 8 + u) * 16 + k4];
#pragma unroll
            for (int nn = 0; nn < 8; ++nn)
#pragma unroll
                for (int pp = 0; pp < 8; ++pp)
                    acc[nn][pp] += a[nn][0] * b[pp][0] + a[nn][1] * b[pp][1]
                                 + a[nn][2] * b[pp][2] + a[nn][3] * b[pp][3];
        }
    }
#pragma unroll
    for (int nn = 0; nn < 8; ++nn)
#pragma unroll
        for (int pp = 0; pp < 8; ++pp)
            atomicAdd(&m1[(tn * 8 + nn) * 128 + tp * 8 + pp], acc[nn][pp]);
}

// ---------- final: out[n] = sigmoid(relu(m1[n,:]) . wm2 + bm2) ----------
__global__ void k_final(const float* __restrict__ m1, const float* __restrict__ wm2,
                        const float* __restrict__ bm2, float* __restrict__ out) {
    int n = threadIdx.x;
    float acc = bm2[0];
    for (int p = 0; p < 128; ++p) acc += fmaxf(m1[n * 128 + p], 0.f) * wm2[p];
    out[n] = 1.f / (1.f + __expf(-acc));
}

// =====================================================================
extern "C" void kernel_launch(void* const* d_in, const int* in_sizes, int n_in,
                              void* d_out, int out_size, void* d_ws, size_t ws_size,
                              hipStream_t stream) {
    const float* x       = (const float*)d_in[0];
    const float* ew      = (const float*)d_in[2];
    const float* w1_rel  = (const float*)d_in[3];
    const float* b1      = (const float*)d_in[4];
    const float* w1_root = (const float*)d_in[5];
    const float* w2_rel  = (const float*)d_in[6];
    const float* b2      = (const float*)d_in[7];
    const float* w2_root = (const float*)d_in[8];
    const float* wm1     = (const float*)d_in[9];
    const float* bm1     = (const float*)d_in[10];
    const float* wm2     = (const float*)d_in[11];
    const float* bm2     = (const float*)d_in[12];
    const float* wih0    = (const float*)d_in[13];
    const float* whh0    = (const float*)d_in[14];
    const float* bih0    = (const float*)d_in[15];
    const float* bhh0    = (const float*)d_in[16];
    const float* wih0r   = (const float*)d_in[17];
    const float* whh0r   = (const float*)d_in[18];
    const float* bih0r   = (const float*)d_in[19];
    const float* bhh0r   = (const float*)d_in[20];
    const float* wih1    = (const float*)d_in[21];
    const float* whh1    = (const float*)d_in[22];
    const float* bih1    = (const float*)d_in[23];
    const float* bhh1    = (const float*)d_in[24];
    const float* wih1r   = (const float*)d_in[25];
    const float* whh1r   = (const float*)d_in[26];
    const float* bih1r   = (const float*)d_in[27];
    const float* bhh1r   = (const float*)d_in[28];

    char* ws = (char*)d_ws;
    // arena (peak 258,029,056 B); phase-2 buffers reuse phase-1 regions
    float* Amat  = (float*)(ws + 0);                  //   524,288
    u16*   xb    = (u16*)  (ws + 1048576);            //  62,914,560
    u16*   w1b   = (u16*)  (ws + 63963136);           //  61,931,520 (reused rel->root)
    float* Grel  = (float*)(ws + 125894656);          //  66,060,288
    float* Groot = (float*)(ws + 191968768);          //  66,060,288
    u16*   h1b   = (u16*)  (ws + 1048576);            //  33,030,144 (over dead xb)
    u16*   w2b   = (u16*)  (ws + 34078720);           //   4,128,768 (reused rel->root)
    float* G2rel = (float*)(ws + 38207488);           //   8,388,608
    float* G2root= (float*)(ws + 46596096);           //   8,388,608
    float* h2    = (float*)(ws + 54984704);           //   8,388,608
    float* xg0f  = (float*)(ws + 63373312);           //  33,554,432
    float* xg0r  = (float*)(ws + 96927744);           //  33,554,432
    float* hs0f  = (float*)(ws + 130482176);          //   8,388,608
    float* hs0r  = (float*)(ws + 138870784);          //   8,388,608
    float* xg1f  = (float*)(ws + 147259392);          //  33,554,432
    float* xg1r  = (float*)(ws + 180813824);          //  33,554,432
    float* hs1f  = (float*)(ws + 214368256);          //   8,388,608
    float* hs1r  = (float*)(ws + 222756864);          //   8,388,608
    float* m1    = (float*)(ws + 231145472);          //      65,536

    // --- GNN layer 1: G = X @ W^T (bf16 MFMA), then per-batch aggregate ---
    k_cvt<<<15360, 256, 0, stream>>>(x, xb);                       // 31,457,280 elems
    k_buildA<<<512, 256, 0, stream>>>(ew, Amat);
    k_cvt<<<15120, 256, 0, stream>>>(w1_rel, w1b);                 // 30,965,760
    k_gemm<<<dim3(32, 32), 256, 0, stream>>>(xb, w1b, Grel, 4096, 4032, 7680);
    k_cvt<<<15120, 256, 0, stream>>>(w1_root, w1b);
    k_gemm<<<dim3(32, 32), 256, 0, stream>>>(xb, w1b, Groot, 4096, 4032, 7680);
    k_agg<4032, true><<<128, 256, 0, stream>>>(Grel, Groot, Amat, b1, (void*)h1b);

    // --- GNN layer 2 ---
    k_cvt<<<1008, 256, 0, stream>>>(w2_rel, w2b);                  // 2,064,384
    k_gemm<<<dim3(4, 32), 256, 0, stream>>>(h1b, w2b, G2rel, 4096, 512, 4032);
    k_cvt<<<1008, 256, 0, stream>>>(w2_root, w2b);
    k_gemm<<<dim3(4, 32), 256, 0, stream>>>(h1b, w2b, G2root, 4096, 512, 4032);
    k_agg<512, false><<<128, 256, 0, stream>>>(G2rel, G2root, Amat, b2, (void*)h2);

    // --- LSTM layer 0 (seq[t][n][c] = h2[n*32+c][t]) ---
    k_xg0<<<512, 256, 0, stream>>>(h2, wih0, bih0, bhh0, wih0r, bih0r, bhh0r, xg0f, xg0r);
    k_lstm<<<32, 256, 0, stream>>>(xg0f, xg0r, whh0, whh0r, hs0f, hs0r);

    // --- LSTM layer 1 (input = concat(fwd,bwd)) ---
    k_xg1<<<512, 256, 0, stream>>>(hs0f, hs0r, wih1, bih1, bhh1, wih1r, bih1r, bhh1r, xg1f, xg1r);
    k_lstm<<<32, 256, 0, stream>>>(xg1f, xg1r, whh1, whh1r, hs1f, hs1r);

    // --- final MLP + sigmoid ---
    k_m1init<<<64, 256, 0, stream>>>(m1, bm1);
    k_mlp<<<128, 256, 0, stream>>>(hs1f, hs1r, wm1, m1);
    k_final<<<1, 128, 0, stream>>>(m1, wm2, bm2, (float*)d_out);
}

// Round 2
// 2375.542 us; speedup vs baseline: 1.2621x; 1.2621x over previous
//
#include <hip/hip_runtime.h>

typedef unsigned short u16;
typedef unsigned int u32;
typedef float f32x4 __attribute__((ext_vector_type(4)));
typedef short s16x8 __attribute__((ext_vector_type(8)));
typedef u16 u16x4 __attribute__((ext_vector_type(4)));
typedef u16 u16x8 __attribute__((ext_vector_type(8)));

// ---------- helpers ----------
__device__ __forceinline__ u16 f2bf(float x) {           // RNE f32->bf16
    u32 u = __builtin_bit_cast(u32, x);
    u += 0x7fffu + ((u >> 16) & 1u);
    return (u16)(u >> 16);
}
__device__ __forceinline__ float bf2f(u16 v) {
    u32 u = ((u32)v) << 16;
    return __builtin_bit_cast(float, u);
}
__device__ __forceinline__ float sigm(float x) { return 1.f / (1.f + __expf(-x)); }
__device__ __forceinline__ float tanh_fast(float x) {
    float e = __expf(-2.f * fabsf(x));
    float t = (1.f - e) / (1.f + e);
    return copysignf(t, x);
}
__device__ __forceinline__ void gload16(const void* g, void* l) {
    __builtin_amdgcn_global_load_lds((const __attribute__((address_space(1))) void*)g,
                                     (__attribute__((address_space(3))) void*)l, 16, 0, 0);
}
__device__ __forceinline__ void mfma_bf16(s16x8 a, s16x8 b, f32x4& acc) {
    asm volatile("v_mfma_f32_16x16x32_bf16 %0, %1, %2, %0" : "+v"(acc) : "v"(a), "v"(b));
}

// ---------- f32 -> bf16 with row repack: out[row*ostride + coff + c] ----------
__global__ __launch_bounds__(256) void k_cvt_pack(const float* __restrict__ in, u16* __restrict__ out,
                                                  int ncols8, long ostride, int coff) {
    long i = (long)blockIdx.x * 256 + threadIdx.x;
    long row = i / ncols8;
    int c8 = (int)(i - row * ncols8);
    const f32x4* p = (const f32x4*)(in + (row * ncols8 + c8) * 8);
    f32x4 a = p[0], b = p[1];
    u16x8 v;
    v[0] = f2bf(a[0]); v[1] = f2bf(a[1]); v[2] = f2bf(a[2]); v[3] = f2bf(a[3]);
    v[4] = f2bf(b[0]); v[5] = f2bf(b[1]); v[6] = f2bf(b[2]); v[7] = f2bf(b[3]);
    *(u16x8*)(out + row * ostride + coff + (long)c8 * 8) = v;
}

// ---------- A[b][d][s] = ew[b*1024 + s*32 + d] / 32 ----------
__global__ __launch_bounds__(256) void k_buildA(const float* __restrict__ ew, float* __restrict__ A) {
    int i = blockIdx.x * 256 + threadIdx.x;           // 131072 total
    int b = i >> 10, rem = i & 1023, s = rem >> 5, d = rem & 31;
    A[(b << 10) + (d << 5) + s] = ew[i] * 0.03125f;
}

// ---------- Z[(b,d)][k] = bf16( sum_s A[b][d][s] * x[(b,s)][k] ), k-chunked ----------
__global__ __launch_bounds__(256) void k_aggX(const float* __restrict__ x, const float* __restrict__ A,
                                              u16* __restrict__ Z) {
    __shared__ float lA[1024];
    const int b = blockIdx.y, kc = blockIdx.x;        // kc 0..59
    for (int i = threadIdx.x; i < 1024; i += 256) lA[i] = A[(b << 10) + i];
    __syncthreads();
    const int d0 = (threadIdx.x >> 5) * 4;
    const int k0 = kc * 128 + (threadIdx.x & 31) * 4;
    const float* xb = x + (size_t)b * 32 * 7680 + k0;
    f32x4 acc[4] = {};
    for (int s = 0; s < 32; ++s) {
        f32x4 v = *(const f32x4*)(xb + (size_t)s * 7680);
#pragma unroll
        for (int dd = 0; dd < 4; ++dd) acc[dd] += lA[(d0 + dd) * 32 + s] * v;
    }
#pragma unroll
    for (int dd = 0; dd < 4; ++dd) {
        u16x4 v; v[0] = f2bf(acc[dd][0]); v[1] = f2bf(acc[dd][1]);
        v[2] = f2bf(acc[dd][2]); v[3] = f2bf(acc[dd][3]);
        *(u16x4*)(Z + (size_t)(b * 32 + d0 + dd) * 15360 + k0) = v;
    }
}

// ---------- AH[(b,d)][k] = bf16( sum_s A[b][d][s] * h1[(b,s)][k] ), h1 bf16 [4096][4032] ----------
__global__ __launch_bounds__(256) void k_aggH(const u16* __restrict__ h1, const float* __restrict__ A,
                                              u16* __restrict__ AH) {
    __shared__ float lA[1024];
    const int b = blockIdx.y, kc = blockIdx.x;        // kc 0..31
    for (int i = threadIdx.x; i < 1024; i += 256) lA[i] = A[(b << 10) + i];
    __syncthreads();
    const int d0 = (threadIdx.x >> 5) * 4;
    const int k0 = kc * 128 + (threadIdx.x & 31) * 4;
    if (k0 >= 4032) return;
    const u16* hb = h1 + (size_t)b * 32 * 4032 + k0;
    f32x4 acc[4] = {};
    for (int s = 0; s < 32; ++s) {
        u16x4 hv = *(const u16x4*)(hb + (size_t)s * 4032);
        f32x4 v; v[0] = bf2f(hv[0]); v[1] = bf2f(hv[1]); v[2] = bf2f(hv[2]); v[3] = bf2f(hv[3]);
#pragma unroll
        for (int dd = 0; dd < 4; ++dd) acc[dd] += lA[(d0 + dd) * 32 + s] * v;
    }
#pragma unroll
    for (int dd = 0; dd < 4; ++dd) {
        u16x4 v; v[0] = f2bf(acc[dd][0]); v[1] = f2bf(acc[dd][1]);
        v[2] = f2bf(acc[dd][2]); v[3] = f2bf(acc[dd][3]);
        *(u16x4*)(AH + (size_t)(b * 32 + d0 + dd) * 4032 + k0) = v;
    }
}

// ---------- bf16 GEMM  C = [A1|A2] @ [B1|B2]^T + bias, relu  (m97 structure, 2 K-segments) ----------
// 128x128 tile, BK=32, 256 thr (4 waves 2x2). M = grid.y*128, ragged Ncols supported, K%32==0.
template <bool BF16OUT>
__global__ __launch_bounds__(256) void k_gemm(
    const u16* __restrict__ A1, const u16* __restrict__ B1, int K1,
    const u16* __restrict__ A2, const u16* __restrict__ B2, int K2,
    void* __restrict__ Cv, const float* __restrict__ bias, int ldc, int Ncols) {
    __shared__ u16 lA[4096], lB[4096];
    const int tid = threadIdx.x, wave = tid >> 6, lane = tid & 63;
    const int n0 = blockIdx.x * 128, m0 = blockIdx.y * 128;
    const int srow = tid >> 2, scol = (tid & 3) * 8;
    u16* lAw0 = lA + wave * 512; u16* lAw1 = lA + 2048 + wave * 512;
    u16* lBw0 = lB + wave * 512; u16* lBw1 = lB + 2048 + wave * 512;
    const int wm = wave >> 1, wn = wave & 1;
    const int fr = lane & 15, fk = (lane >> 4) * 8;
    int br0 = n0 + srow;      if (br0 > Ncols - 1) br0 = Ncols - 1;
    int br1 = n0 + 64 + srow; if (br1 > Ncols - 1) br1 = Ncols - 1;

    f32x4 acc[4][4] = {};
    for (int seg = 0; seg < 2; ++seg) {
        const u16* As = seg ? A2 : A1;
        const u16* Bs = seg ? B2 : B1;
        const int  Ks = seg ? K2 : K1;
        const u16* gA0 = As + (size_t)(m0 + srow) * Ks + scol;
        const u16* gA1 = gA0 + (size_t)64 * Ks;
        const u16* gB0 = Bs + (size_t)br0 * Ks + scol;
        const u16* gB1 = Bs + (size_t)br1 * Ks + scol;
        for (int kt = 0; kt < Ks; kt += 32) {
            gload16(gA0 + kt, lAw0);
            gload16(gA1 + kt, lAw1);
            gload16(gB0 + kt, lBw0);
            gload16(gB1 + kt, lBw1);
            __syncthreads();                           // drains vmcnt
            s16x8 av[4], bv[4];
#pragma unroll
            for (int i = 0; i < 4; ++i) av[i] = *(const s16x8*)(lA + (wm * 64 + i * 16 + fr) * 32 + fk);
#pragma unroll
            for (int j = 0; j < 4; ++j) bv[j] = *(const s16x8*)(lB + (wn * 64 + j * 16 + fr) * 32 + fk);
#pragma unroll
            for (int i = 0; i < 4; ++i)
#pragma unroll
                for (int j = 0; j < 4; ++j)
                    mfma_bf16(av[i], bv[j], acc[i][j]);
            __syncthreads();
        }
    }
    const int rowb = m0 + wm * 64 + ((lane >> 4) << 2);
    const int colb = n0 + wn * 64 + (lane & 15);
#pragma unroll
    for (int i = 0; i < 4; ++i)
#pragma unroll
        for (int j = 0; j < 4; ++j) {
            int col = colb + j * 16;
            if (col < Ncols) {
                float bv = bias[col];
#pragma unroll
                for (int r = 0; r < 4; ++r) {
                    float v = acc[i][j][r] + bv;
                    v = fmaxf(v, 0.f);
                    size_t o = (size_t)(rowb + i * 16 + r) * ldc + col;
                    if (BF16OUT) ((u16*)Cv)[o] = f2bf(v);
                    else         ((float*)Cv)[o] = v;
                }
            }
        }
}

// ---------- h2 [4096][512] -> h2T [512][4096] ----------
__global__ __launch_bounds__(256) void k_transpose(const float* __restrict__ in, float* __restrict__ out) {
    __shared__ float t[32][33];
    const int c0 = blockIdx.x * 32, r0 = blockIdx.y * 32;
    const int tx = threadIdx.x & 31, ty = threadIdx.x >> 5;   // ty 0..7
#pragma unroll
    for (int i = 0; i < 4; ++i)
        t[ty * 4 + i][tx] = in[(size_t)(r0 + ty * 4 + i) * 512 + c0 + tx];
    __syncthreads();
#pragma unroll
    for (int i = 0; i < 4; ++i)
        out[(size_t)(c0 + ty * 4 + i) * 4096 + r0 + tx] = t[tx][ty * 4 + i];
}

// ---------- LSTM layer-0 input projection (h2T coalesced) ----------
__global__ __launch_bounds__(256) void k_xg0(const float* __restrict__ h2T,
    const float* __restrict__ wihf, const float* __restrict__ bihf, const float* __restrict__ bhhf,
    const float* __restrict__ wihr, const float* __restrict__ bihr, const float* __restrict__ bhhr,
    float* __restrict__ xgf, float* __restrict__ xgr) {
    __shared__ float col[4096];
    const int t = blockIdx.x;
    const f32x4* src = (const f32x4*)(h2T + (size_t)t * 4096);
    for (int r = threadIdx.x; r < 1024; r += 256) ((f32x4*)col)[r] = src[r];
    __syncthreads();
    const int dir = threadIdx.x >> 7, g = threadIdx.x & 127;
    const float* wih = dir ? wihr : wihf;
    const float bias = dir ? (bihr[g] + bhhr[g]) : (bihf[g] + bhhf[g]);
    f32x4 w[8];
#pragma unroll
    for (int q = 0; q < 8; ++q) w[q] = *(const f32x4*)(wih + g * 32 + q * 4);
    float* out = dir ? xgr : xgf;
    const f32x4* c4 = (const f32x4*)col;
    for (int n = 0; n < 128; ++n) {
        float acc = bias;
#pragma unroll
        for (int q = 0; q < 8; ++q) {
            f32x4 v = c4[n * 8 + q];
            acc += w[q][0] * v[0] + w[q][1] * v[1] + w[q][2] * v[2] + w[q][3] * v[3];
        }
        out[((size_t)t * 128 + n) * 128 + g] = acc;
    }
}

// ---------- LSTM layer-1 input projection ----------
__global__ __launch_bounds__(256) void k_xg1(const float* __restrict__ hf, const float* __restrict__ hr,
    const float* __restrict__ wihf, const float* __restrict__ bihf, const float* __restrict__ bhhf,
    const float* __restrict__ wihr, const float* __restrict__ bihr, const float* __restrict__ bhhr,
    float* __restrict__ xgf, float* __restrict__ xgr) {
    __shared__ float sin_[8192];
    const int t = blockIdx.x;
    for (int idx = threadIdx.x; idx < 8192; idx += 256) {
        int n = idx >> 6, c = idx & 63;
        sin_[idx] = (c < 32) ? hf[((size_t)t * 128 + n) * 32 + c]
                             : hr[((size_t)t * 128 + n) * 32 + (c & 31)];
    }
    __syncthreads();
    const int dir = threadIdx.x >> 7, g = threadIdx.x & 127;
    const float* wih = dir ? wihr : wihf;
    const float bias = dir ? (bihr[g] + bhhr[g]) : (bihf[g] + bhhf[g]);
    f32x4 w[16];
#pragma unroll
    for (int q = 0; q < 16; ++q) w[q] = *(const f32x4*)(wih + g * 64 + q * 4);
    float* out = dir ? xgr : xgf;
    const f32x4* s4 = (const f32x4*)sin_;
    for (int n = 0; n < 128; ++n) {
        float acc = bias;
#pragma unroll
        for (int q = 0; q < 16; ++q) {
            f32x4 v = s4[n * 16 + q];
            acc += w[q][0] * v[0] + w[q][1] * v[1] + w[q][2] * v[2] + w[q][3] * v[3];
        }
        out[((size_t)t * 128 + n) * 128 + g] = acc;
    }
}

// ---------- LSTM recurrence with next-step gate prefetch ----------
__global__ __launch_bounds__(256) void k_lstm(const float* __restrict__ xgf, const float* __restrict__ xgr,
                                              const float* __restrict__ whhf, const float* __restrict__ whhr,
                                              float* __restrict__ hsf, float* __restrict__ hsr) {
    const int dir = blockIdx.x >> 4;
    const int n0 = (blockIdx.x & 15) * 8;
    const int bl = threadIdx.x >> 5, j = threadIdx.x & 31;
    const float* xg = dir ? xgr : xgf;
    const float* whh = dir ? whhr : whhf;
    float* hs = dir ? hsr : hsf;
    __shared__ float hb[256];
    f32x4 w[4][8];
#pragma unroll
    for (int q = 0; q < 4; ++q)
#pragma unroll
        for (int k = 0; k < 8; ++k)
            w[q][k] = *(const f32x4*)(whh + (size_t)(q * 32 + j) * 32 + k * 4);
    hb[threadIdx.x] = 0.f;
    float c = 0.f;
    __syncthreads();
    const f32x4* hb4 = (const f32x4*)hb;
    // prefetch gates for first step
    int tt = dir ? 511 : 0;
    const float* xp = xg + ((size_t)tt * 128 + n0 + bl) * 128;
    float xi = xp[j], xf = xp[32 + j], xc = xp[64 + j], xo = xp[96 + j];
    for (int ts = 0; ts < 512; ++ts) {
        float ni = 0.f, nf = 0.f, ng = 0.f, no = 0.f;
        if (ts < 511) {
            const int tn = dir ? (510 - ts) : (ts + 1);
            const float* xq = xg + ((size_t)tn * 128 + n0 + bl) * 128;
            ni = xq[j]; nf = xq[32 + j]; ng = xq[64 + j]; no = xq[96 + j];
        }
        float gi = xi, gf = xf, gg = xc, go = xo;
#pragma unroll
        for (int k = 0; k < 8; ++k) {
            f32x4 hv = hb4[bl * 8 + k];
            gi += w[0][k][0] * hv[0] + w[0][k][1] * hv[1] + w[0][k][2] * hv[2] + w[0][k][3] * hv[3];
            gf += w[1][k][0] * hv[0] + w[1][k][1] * hv[1] + w[1][k][2] * hv[2] + w[1][k][3] * hv[3];
            gg += w[2][k][0] * hv[0] + w[2][k][1] * hv[1] + w[2][k][2] * hv[2] + w[2][k][3] * hv[3];
            go += w[3][k][0] * hv[0] + w[3][k][1] * hv[1] + w[3][k][2] * hv[2] + w[3][k][3] * hv[3];
        }
        c = sigm(gf) * c + sigm(gi) * tanh_fast(gg);
        float h = sigm(go) * tanh_fast(c);
        const int tcur = dir ? (511 - ts) : ts;
        hs[((size_t)tcur * 128 + n0 + bl) * 32 + j] = h;
        __syncthreads();
        hb[threadIdx.x] = h;
        __syncthreads();
        xi = ni; xf = nf; xc = ng; xo = no;
    }
}

// ---------- m1 init to bias ----------
__global__ __launch_bounds__(256) void k_m1init(float* __restrict__ m1, const float* __restrict__ bm1) {
    int i = blockIdx.x * 256 + threadIdx.x;
    m1[i] = bm1[i & 127];
}

// ---------- split-K MLP: block = 4 time-steps, atomicAdd partials into m1[n][p] ----------
__global__ __launch_bounds__(256) void k_mlp(const float* __restrict__ hf, const float* __restrict__ hr,
                                             const float* __restrict__ wm1, float* __restrict__ m1) {
    __shared__ float sa[8192], sb[8192];
    const int t0 = blockIdx.x * 4;
    const int tn = threadIdx.x >> 4, tp = threadIdx.x & 15;
    float acc[8][8] = {};
    for (int t = t0; t < t0 + 4; ++t) {
        __syncthreads();
        for (int idx = threadIdx.x; idx < 8192; idx += 256) {
            int n = idx >> 6, k = idx & 63;
            sa[idx] = (k < 32) ? hf[((size_t)t * 128 + n) * 32 + k]
                               : hr[((size_t)t * 128 + n) * 32 + (k & 31)];
            sb[idx] = wm1[(size_t)n * 32768 + t * 64 + k];
        }
        __syncthreads();
        const f32x4* sa4 = (const f32x4*)sa;
        const f32x4* sb4 = (const f32x4*)sb;
        for (int k4 = 0; k4 < 16; ++k4) {
            f32x4 a[8], b[8];
#pragma unroll
            for (int u = 0; u < 8; ++u) a[u] = sa4[(tn * 8 + u) * 16 + k4];
#pragma unroll
            for (int u = 0; u < 8; ++u) b[u] = sb4[(tp * 8 + u) * 16 + k4];
#pragma unroll
            for (int nn = 0; nn < 8; ++nn)
#pragma unroll
                for (int pp = 0; pp < 8; ++pp)
                    acc[nn][pp] += a[nn][0] * b[pp][0] + a[nn][1] * b[pp][1]
                                 + a[nn][2] * b[pp][2] + a[nn][3] * b[pp][3];
        }
    }
#pragma unroll
    for (int nn = 0; nn < 8; ++nn)
#pragma unroll
        for (int pp = 0; pp < 8; ++pp)
            atomicAdd(&m1[(tn * 8 + nn) * 128 + tp * 8 + pp], acc[nn][pp]);
}

// ---------- final: out[n] = sigmoid(relu(m1[n,:]) . wm2 + bm2) ----------
__global__ void k_final(const float* __restrict__ m1, const float* __restrict__ wm2,
                        const float* __restrict__ bm2, float* __restrict__ out) {
    int n = threadIdx.x;
    float acc = bm2[0];
    for (int p = 0; p < 128; ++p) acc += fmaxf(m1[n * 128 + p], 0.f) * wm2[p];
    out[n] = 1.f / (1.f + __expf(-acc));
}

// =====================================================================
extern "C" void kernel_launch(void* const* d_in, const int* in_sizes, int n_in,
                              void* d_out, int out_size, void* d_ws, size_t ws_size,
                              hipStream_t stream) {
    const float* x       = (const float*)d_in[0];
    const float* ew      = (const float*)d_in[2];
    const float* w1_rel  = (const float*)d_in[3];
    const float* b1      = (const float*)d_in[4];
    const float* w1_root = (const float*)d_in[5];
    const float* w2_rel  = (const float*)d_in[6];
    const float* b2      = (const float*)d_in[7];
    const float* w2_root = (const float*)d_in[8];
    const float* wm1     = (const float*)d_in[9];
    const float* bm1     = (const float*)d_in[10];
    const float* wm2     = (const float*)d_in[11];
    const float* bm2     = (const float*)d_in[12];
    const float* wih0    = (const float*)d_in[13];
    const float* whh0    = (const float*)d_in[14];
    const float* bih0    = (const float*)d_in[15];
    const float* bhh0    = (const float*)d_in[16];
    const float* wih0r   = (const float*)d_in[17];
    const float* whh0r   = (const float*)d_in[18];
    const float* bih0r   = (const float*)d_in[19];
    const float* bhh0r   = (const float*)d_in[20];
    const float* wih1    = (const float*)d_in[21];
    const float* whh1    = (const float*)d_in[22];
    const float* bih1    = (const float*)d_in[23];
    const float* bhh1    = (const float*)d_in[24];
    const float* wih1r   = (const float*)d_in[25];
    const float* whh1r   = (const float*)d_in[26];
    const float* bih1r   = (const float*)d_in[27];
    const float* bhh1r   = (const float*)d_in[28];

    char* ws = (char*)d_ws;
    // arena, peak 226,426,880 B (< round-0-proven 231 MB)
    float* Amat   = (float*)(ws + 0);              //     524,288
    u16*   Zb     = (u16*)  (ws + 524288);         // 125,829,120  [4096][15360] = [A@X | X]
    u16*   Wc     = (u16*)  (ws + 126353408);      //  61,931,520  [2016][15360] weight chunk
    u16*   h1b    = (u16*)  (ws + 188284928);      //  33,030,144  [4096][4032]
    u16*   AHb    = (u16*)  (ws + 524288);         //  33,030,144  over dead Zb
    u16*   w2relb = (u16*)  (ws + 33554432);       //   4,128,768
    u16*   w2rootb= (u16*)  (ws + 37683200);       //   4,128,768
    float* h2     = (float*)(ws + 41811968);       //   8,388,608  [4096][512]
    float* h2T    = (float*)(ws + 50200576);       //   8,388,608  [512][4096]
    float* xg0f   = (float*)(ws + 58589184);       //  33,554,432
    float* xg0r   = (float*)(ws + 92143616);       //  33,554,432
    float* hs0f   = (float*)(ws + 125698048);      //   8,388,608
    float* hs0r   = (float*)(ws + 134086656);      //   8,388,608
    float* xg1f   = (float*)(ws + 142475264);      //  33,554,432
    float* xg1r   = (float*)(ws + 176029696);      //  33,554,432
    float* hs1f   = (float*)(ws + 209584128);      //   8,388,608
    float* hs1r   = (float*)(ws + 217972736);      //   8,388,608
    float* m1     = (float*)(ws + 226361344);      //      65,536

    // --- GNN layer 1: h1 = relu([A@X | X] @ [W1rel | W1root]^T + b1), one K=15360 GEMM ---
    k_buildA<<<512, 256, 0, stream>>>(ew, Amat);
    k_cvt_pack<<<15360, 256, 0, stream>>>(x, Zb, 960, 15360, 7680);          // X -> Z upper K
    k_aggX<<<dim3(60, 128), 256, 0, stream>>>(x, Amat, Zb);                  // A@X -> Z lower K
    for (int c = 0; c < 2; ++c) {
        k_cvt_pack<<<7560, 256, 0, stream>>>(w1_rel + (size_t)c * 2016 * 7680, Wc, 960, 15360, 0);
        k_cvt_pack<<<7560, 256, 0, stream>>>(w1_root + (size_t)c * 2016 * 7680, Wc, 960, 15360, 7680);
        k_gemm<true><<<dim3(16, 32), 256, 0, stream>>>(
            Zb, Wc, 15360, Zb, Wc, 0,
            (void*)(h1b + c * 2016), b1 + c * 2016, 4032, 2016);
    }

    // --- GNN layer 2: h2 = relu([A@h1 | h1] @ [W2rel | W2root]^T + b2), 2-segment K GEMM ---
    k_aggH<<<dim3(32, 128), 256, 0, stream>>>(h1b, Amat, AHb);
    k_cvt_pack<<<1008, 256, 0, stream>>>(w2_rel, w2relb, 504, 4032, 0);
    k_cvt_pack<<<1008, 256, 0, stream>>>(w2_root, w2rootb, 504, 4032, 0);
    k_gemm<false><<<dim3(4, 32), 256, 0, stream>>>(
        AHb, w2relb, 4032, h1b, w2rootb, 4032,
        (void*)h2, b2, 512, 512);

    // --- LSTM layer 0 (seq[t][n][e] = h2[(n*32+e)][t] -> coalesced via h2T) ---
    k_transpose<<<dim3(16, 128), 256, 0, stream>>>(h2, h2T);
    k_xg0<<<512, 256, 0, stream>>>(h2T, wih0, bih0, bhh0, wih0r, bih0r, bhh0r, xg0f, xg0r);
    k_lstm<<<32, 256, 0, stream>>>(xg0f, xg0r, whh0, whh0r, hs0f, hs0r);

    // --- LSTM layer 1 ---
    k_xg1<<<512, 256, 0, stream>>>(hs0f, hs0r, wih1, bih1, bhh1, wih1r, bih1r, bhh1r, xg1f, xg1r);
    k_lstm<<<32, 256, 0, stream>>>(xg1f, xg1r, whh1, whh1r, hs1f, hs1r);

    // --- final MLP + sigmoid ---
    k_m1init<<<64, 256, 0, stream>>>(m1, bm1);
    k_mlp<<<128, 256, 0, stream>>>(hs1f, hs1r, wm1, m1);
    k_final<<<1, 128, 0, stream>>>(m1, wm2, bm2, (float*)d_out);
}